// Round 8
// baseline (906.984 us; speedup 1.0000x reference)
//
#include <hip/hip_runtime.h>
#include <hip/hip_bf16.h>
#include <type_traits>

using bf16 = __hip_bfloat16;

namespace {

constexpr int B_ = 2;
constexpr int N_ = 4096;
constexpr int C_ = 64;
constexpr int K14_ = 14;
constexpr int KX_ = 8;
constexpr int KP_ = 6;
constexpr int K2_ = 32;
constexpr int OC_ = 64;

__device__ __forceinline__ unsigned pack_f16(float a, float b) {
  _Float16 ha = (_Float16)a, hb = (_Float16)b;
  unsigned short ua = __builtin_bit_cast(unsigned short, ha);
  unsigned short ub = __builtin_bit_cast(unsigned short, hb);
  return (unsigned)ua | ((unsigned)ub << 16);
}

using half2v = __attribute__((ext_vector_type(2))) _Float16;
__device__ __forceinline__ float dot2(unsigned a, unsigned b, float acc) {
#if __has_builtin(__builtin_amdgcn_fdot2)
  return __builtin_amdgcn_fdot2(__builtin_bit_cast(half2v, a),
                                __builtin_bit_cast(half2v, b), acc, false);
#else
  half2v ha = __builtin_bit_cast(half2v, a), hb = __builtin_bit_cast(half2v, b);
  acc = fmaf((float)ha[0], (float)hb[0], acc);
  return fmaf((float)ha[1], (float)hb[1], acc);
#endif
}

// monotone u32 key for f32 (no NaN; -0.0 cannot occur for d = t1 - t2 under RN)
__device__ __forceinline__ unsigned fmono(float d) {
  unsigned u = __float_as_uint(d);
  return u ^ (((int)u < 0) ? 0xFFFFFFFFu : 0x80000000u);
}

// Hierarchical per-lane selection: 8 named groups over dst[64] + taken mask.
#define GRP8_ONE(GV, GS, T) \
  { bool av = !((taken >> (T)) & 1ull); bool bb = av && dst[T] < GV; \
    GV = bb ? dst[T] : GV; GS = bb ? (T) : GS; }
#define GRP8(GV, GS, B) do { GV = 3.0e38f; GS = B; \
  GRP8_ONE(GV, GS, (B)+0) GRP8_ONE(GV, GS, (B)+1) GRP8_ONE(GV, GS, (B)+2) \
  GRP8_ONE(GV, GS, (B)+3) GRP8_ONE(GV, GS, (B)+4) GRP8_ONE(GV, GS, (B)+5) \
  GRP8_ONE(GV, GS, (B)+6) GRP8_ONE(GV, GS, (B)+7) } while (0)
#define GTREE_ONE(GV, GS) { bool bb = GV < pv; pv = bb ? GV : pv; ptt = bb ? GS : ptt; }
#define GTREE() do { pv = gv0; ptt = gs0; \
  GTREE_ONE(gv1, gs1) GTREE_ONE(gv2, gs2) GTREE_ONE(gv3, gs3) GTREE_ONE(gv4, gs4) \
  GTREE_ONE(gv5, gs5) GTREE_ONE(gv6, gs6) GTREE_ONE(gv7, gs7) } while (0)
#define GRP_SWITCH(TT) do { switch ((TT) >> 3) { \
  case 0: GRP8(gv0, gs0, 0);  break; case 1: GRP8(gv1, gs1, 8);  break; \
  case 2: GRP8(gv2, gs2, 16); break; case 3: GRP8(gv3, gs3, 24); break; \
  case 4: GRP8(gv4, gs4, 32); break; case 5: GRP8(gv5, gs5, 40); break; \
  case 6: GRP8(gv6, gs6, 48); break; case 7: GRP8(gv7, gs7, 56); break; } \
  GTREE(); } while (0)
#define SEL_DECL float gv0, gv1, gv2, gv3, gv4, gv5, gv6, gv7; \
  int gs0, gs1, gs2, gs3, gs4, gs5, gs6, gs7; float pv; int ptt; \
  unsigned long long taken = 0ull;
#define SEL_INIT do { \
  GRP8(gv0, gs0, 0);  GRP8(gv1, gs1, 8);  GRP8(gv2, gs2, 16); GRP8(gv3, gs3, 24); \
  GRP8(gv4, gs4, 32); GRP8(gv5, gs5, 40); GRP8(gv6, gs6, 48); GRP8(gv7, gs7, 56); \
  GTREE(); } while (0)

// ---------------- x squared norms (f32) ----------------
__global__ __launch_bounds__(256)
void xnorm_kernel(const float* __restrict__ x, float* __restrict__ nx)
{
  int p = blockIdx.x * 256 + threadIdx.x;
  if (p >= B_ * N_) return;
  float s = 0.f;
#pragma unroll 8
  for (int c = 0; c < C_; ++c) { float v = x[p * C_ + c]; s = fmaf(v, v, s); }
  nx[p] = s;
}

// ---------------- weight prep: split + transpose ----------------
__global__ __launch_bounds__(256)
void wprep_kernel(const float* __restrict__ W1, const float* __restrict__ W2,
                  const float* __restrict__ W3,
                  float* __restrict__ WT1a, float* __restrict__ WT1bm,
                  float* __restrict__ WT2a, float* __restrict__ WT2bm,
                  float* __restrict__ W3T)
{
  int idx = blockIdx.x * 256 + threadIdx.x;
  if (idx < 128 * 128) {
    int o = idx & 127, c = idx >> 7;
    float a = W2[o * 256 + c];
    WT2a[c * 128 + o] = a;
    WT2bm[c * 128 + o] = W2[o * 256 + 128 + c] - a;
    if (c < 64) {
      float a1 = W1[o * 128 + c];
      WT1a[c * 128 + o] = a1;
      WT1bm[c * 128 + o] = W1[o * 128 + 64 + c] - a1;
    }
  }
  if (idx < 64 * 128) {
    int oo = idx & 63, c = idx >> 6;
    W3T[c * 64 + oo] = W3[oo * 128 + c];
  }
}

// ---------------- knn over x v4: f16 dot2, q in SGPRs, conflict-free b32 LDS ----
// tileh[j][c2] u32 = f16 pair (c=2c2, 2c2+1) of neighbor j; row stride 33 (odd).
// Lane owns neighbors {nb4*64+lane}; slot tt = ti*4+nb4 -> j = ti*256+nb4*64+lane
// (monotonic in tt for fixed lane).
__global__ __launch_bounds__(512, 4)
void knn_x_kernel(const float* __restrict__ x, const float* __restrict__ nx,
                  int* __restrict__ idx1)
{
  __shared__ unsigned tileh[256 * 33];     // 33 KB
  const int wave = threadIdx.x >> 6, lane = threadIdx.x & 63;
  const int qg = blockIdx.x * 8 + wave;    // 1024 blocks * 8 waves
  const int bb = qg >> 12;
  const float* xb = x + bb * N_ * C_;
  // query row -> 32 packed f16 pairs, broadcast to SGPRs via readlane
  unsigned myq;
  {
    float2 qv = *(const float2*)&x[qg * C_ + 2 * (lane & 31)];
    myq = pack_f16(qv.x, qv.y);
  }
  unsigned qp[32];
#pragma unroll
  for (int c2 = 0; c2 < 32; ++c2) qp[c2] = __builtin_amdgcn_readlane(myq, c2);
  const float nq = nx[qg];
  const float* nb_ = nx + bb * N_;
  float dst[64];
#pragma unroll
  for (int ti = 0; ti < 16; ++ti) {
    __syncthreads();
    for (int e = threadIdx.x; e < 256 * 32; e += 512) {
      int c2 = e & 31, j = e >> 5;
      float2 v = *(const float2*)&xb[(ti * 256 + j) * C_ + 2 * c2];
      tileh[j * 33 + c2] = pack_f16(v.x, v.y);
    }
    __syncthreads();
#pragma unroll
    for (int nb4 = 0; nb4 < 4; ++nb4) {
      const unsigned* row = &tileh[(nb4 * 64 + lane) * 33];
      float acc = 0.f;
#pragma unroll
      for (int c2 = 0; c2 < 32; ++c2) acc = dot2(qp[c2], row[c2], acc);
      float nbv = nb_[ti * 256 + nb4 * 64 + lane];
      dst[ti * 4 + nb4] = nq + nbv - 2.f * acc;
    }
  }
  SEL_DECL;
  SEL_INIT;
  for (int r = 0; r < KX_ + 1; ++r) {
    int j = ((ptt >> 2) << 8) + ((ptt & 3) << 6) + lane;
    unsigned long long key = ((unsigned long long)fmono(pv) << 32) | (unsigned)j;
#pragma unroll
    for (int m = 1; m < 64; m <<= 1) {
      unsigned long long ok = __shfl_xor(key, m, 64);
      key = ok < key ? ok : key;
    }
    int wj = (int)(key & 0xFFFFFFFFull);
    if (r > 0 && lane == 0) idx1[qg * K14_ + (r - 1)] = wj;
    if ((wj & 63) == lane) {
      int tt = ((wj >> 8) << 2) | ((wj >> 6) & 3);
      taken |= 1ull << tt;
      GRP_SWITCH(tt);
    }
  }
}

// ---------------- knn over pos: bit-exact numpy-f32 distances (graded idx2) -----
// Distance arithmetic UNCHANGED from the passing R5-R7 version. Butterfly uses
// packed u64 key (mono(d)<<32 | j) — identical ordering (no -0.0/NaN possible).
__global__ __launch_bounds__(512, 2)
void knn_pos_kernel(const float* __restrict__ pos,
                    int* __restrict__ idx1, int* __restrict__ idx2,
                    float* __restrict__ oidx)
{
#pragma clang fp contract(off)
  __shared__ float pL[3][N_];
  __shared__ float nL[N_];
  const int wave = threadIdx.x >> 6, lane = threadIdx.x & 63;
  const int qg = blockIdx.x * 8 + wave;
  const int bb = qg >> 12;
  const float* pb = pos + bb * N_ * 3;
  for (int j = threadIdx.x; j < N_; j += 512) {
    float a = pb[j * 3], b = pb[j * 3 + 1], c = pb[j * 3 + 2];
    pL[0][j] = a; pL[1][j] = b; pL[2][j] = c;
    float aa = a * a;
    float bb2 = b * b;
    float cc = c * c;
    float s1 = aa + bb2;
    nL[j] = s1 + cc;
  }
  __syncthreads();
  const int q = qg & (N_ - 1);
  const float qx = pL[0][q], qy = pL[1][q], qz = pL[2][q];
  const float nq = nL[q];
  float dst[64];
#pragma unroll
  for (int t = 0; t < 64; ++t) {
    int j = t * 64 + lane;
    float dot = qx * pL[0][j];
    dot = fmaf(qy, pL[1][j], dot);
    dot = fmaf(qz, pL[2][j], dot);
    float t1 = nq + nL[j];
    float t2 = 2.0f * dot;
    dst[t] = t1 - t2;
  }
  SEL_DECL;
  SEL_INIT;
  for (int r = 0; r < K2_ + 1; ++r) {
    int j = ptt * 64 + lane;
    unsigned long long key = ((unsigned long long)fmono(pv) << 32) | (unsigned)j;
#pragma unroll
    for (int m = 1; m < 64; m <<= 1) {
      unsigned long long ok = __shfl_xor(key, m, 64);
      key = ok < key ? ok : key;
    }
    int wj = (int)(key & 0xFFFFFFFFull);
    if (r > 0 && lane == 0) {
      int rr = r - 1;
      if (rr < KP_) idx1[qg * K14_ + KX_ + rr] = wj;
      idx2[qg * K2_ + rr] = wj;
      oidx[qg * K2_ + rr] = (float)wj;
    }
    if ((wj & 63) == lane) {
      int tt = wj >> 6;
      taken |= 1ull << tt;
      GRP_SWITCH(tt);
    }
  }
}

// ---------------- per-point projection ----------------
template<int CIN, typename TIN>
__global__ __launch_bounds__(256)
void lin_kernel(const TIN* __restrict__ in, const float* __restrict__ WT,
                bf16* __restrict__ out)
{
  __shared__ float wt[CIN * 128];
  for (int e = threadIdx.x; e < CIN * 128; e += 256) wt[e] = WT[e];
  __syncthreads();
  const int which = threadIdx.x >> 7, o = threadIdx.x & 127;
  for (int p0 = blockIdx.x * 2; p0 < B_ * N_; p0 += gridDim.x * 2) {
    int p = p0 + which;
    float acc = 0.f;
#pragma unroll 8
    for (int c = 0; c < CIN; ++c) {
      float v;
      if constexpr (std::is_same_v<TIN, float>) v = in[p * CIN + c];
      else v = __bfloat162float(in[p * CIN + c]);
      acc = fmaf(wt[c * 128 + o], v, acc);
    }
    out[p * 128 + o] = __float2bfloat16(acc);
  }
}

// ---------------- BN stats over gathered y = a[nbr] + ac[ctr] ----------------
template<int KNB>
__global__ __launch_bounds__(256)
void stats_gather_kernel(const bf16* __restrict__ a, const bf16* __restrict__ ac,
                         const int* __restrict__ nbr, double* __restrict__ st)
{
  const int o = threadIdx.x & 127;
  const int which = threadIdx.x >> 7;
  double s = 0.0, s2 = 0.0;
  const int E = B_ * N_ * KNB;
  for (int e0 = blockIdx.x * 2; e0 < E; e0 += gridDim.x * 2) {
    int e = e0 + which;
    int p = e / KNB;
    int nb = nbr[e] & (N_ - 1);
    int base = (p >> 12) << 12;
    float y = __bfloat162float(a[(base + nb) * 128 + o]) + __bfloat162float(ac[p * 128 + o]);
    s += (double)y; s2 += (double)y * (double)y;
  }
  atomicAdd(&st[o], s);
  atomicAdd(&st[128 + o], s2);
}

// ---------------- BN finalize ----------------
__global__ void bnfin_kernel(const double* __restrict__ st, const float* __restrict__ g,
                             const float* __restrict__ bi, float* __restrict__ so,
                             int nch, double cnt)
{
  int o = threadIdx.x;
  if (o >= nch) return;
  double mu = st[o] / cnt;
  double var = st[nch + o] / cnt - mu * mu;
  double sc = (double)g[o] / sqrt(var + 1e-5);
  so[o] = (float)sc;
  so[nch + o] = (float)((double)bi[o] - mu * sc);
}

// ---------------- h1 = max_k lrelu(bn(u[nbr]+uc[ctr])) ----------------
__global__ __launch_bounds__(256)
void h1_kernel(const bf16* __restrict__ u, const bf16* __restrict__ uc,
               const int* __restrict__ idx1, const float* __restrict__ so,
               bf16* __restrict__ h1)
{
  const int o = threadIdx.x & 127, which = threadIdx.x >> 7;
  float sc = so[o], off = so[128 + o];
  for (int p0 = blockIdx.x * 2; p0 < B_ * N_; p0 += gridDim.x * 2) {
    int p = p0 + which;
    int base = (p >> 12) << 12;
    float ucv = __bfloat162float(uc[p * 128 + o]);
    float m = -3.0e38f;
#pragma unroll
    for (int kk = 0; kk < K14_; ++kk) {
      int nb = idx1[p * K14_ + kk] & (N_ - 1);
      float y = __bfloat162float(u[(base + nb) * 128 + o]) + ucv;
      float v = fmaf(y, sc, off);
      v = v > 0.f ? v : 0.2f * v;
      m = fmaxf(m, v);
    }
    h1[p * 128 + o] = __float2bfloat16(m);
  }
}

// ---------------- conv3: point-major, wave-autonomous, no block barriers -------
template<int PASS>
__global__ __launch_bounds__(256)
void conv3_kernel(const bf16* __restrict__ z, const bf16* __restrict__ zc,
                  const int* __restrict__ idx2, const float* __restrict__ so2,
                  const float* __restrict__ so3, const float* __restrict__ W3T,
                  double* __restrict__ st3, float* __restrict__ outp)
{
  __shared__ float w3[128 * 64];
  __shared__ float h2s[4][128 * 12];
  for (int e = threadIdx.x; e < 128 * 64; e += 256) w3[e] = W3T[e];
  __syncthreads();
  const int wave = threadIdx.x >> 6, lane = threadIdx.x & 63;
  float* h2w = &h2s[wave][0];
  const float sc20 = so2[lane],      off20 = so2[128 + lane];
  const float sc21 = so2[64 + lane], off21 = so2[192 + lane];
  float sc3 = 0.f, off3 = 0.f;
  if constexpr (PASS == 1) { sc3 = so3[lane]; off3 = so3[64 + lane]; }
  double s = 0.0, s2 = 0.0;
  const int gw = blockIdx.x * 4 + wave;
  const int stride = gridDim.x * 4;
  for (int p = gw; p < B_ * N_; p += stride) {
    const int base = (p >> 12) << 12;
    const float zc0 = __bfloat162float(zc[p * 128 + lane]);
    const float zc1 = __bfloat162float(zc[p * 128 + 64 + lane]);
    float m = -3.0e38f;
#pragma unroll
    for (int kc = 0; kc < 4; ++kc) {
      asm volatile("s_waitcnt lgkmcnt(0)" ::: "memory");
#pragma unroll
      for (int i = 0; i < 8; ++i) {
        int nb = idx2[p * K2_ + kc * 8 + i] & (N_ - 1);
        float y0 = __bfloat162float(z[(base + nb) * 128 + lane]) + zc0;
        float y1 = __bfloat162float(z[(base + nb) * 128 + 64 + lane]) + zc1;
        float v0 = fmaf(y0, sc20, off20); v0 = v0 > 0.f ? v0 : 0.2f * v0;
        float v1 = fmaf(y1, sc21, off21); v1 = v1 > 0.f ? v1 : 0.2f * v1;
        h2w[lane * 12 + i] = v0;
        h2w[(lane + 64) * 12 + i] = v1;
      }
      asm volatile("s_waitcnt lgkmcnt(0)" ::: "memory");
      float a0 = 0.f, a1 = 0.f, a2 = 0.f, a3 = 0.f;
      float a4 = 0.f, a5 = 0.f, a6 = 0.f, a7 = 0.f;
#pragma unroll 4
      for (int c = 0; c < 128; ++c) {
        float wv = w3[(c << 6) | lane];
        float4 ha = *(const float4*)&h2w[c * 12];
        float4 hb = *(const float4*)&h2w[c * 12 + 4];
        a0 = fmaf(wv, ha.x, a0); a1 = fmaf(wv, ha.y, a1);
        a2 = fmaf(wv, ha.z, a2); a3 = fmaf(wv, ha.w, a3);
        a4 = fmaf(wv, hb.x, a4); a5 = fmaf(wv, hb.y, a5);
        a6 = fmaf(wv, hb.z, a6); a7 = fmaf(wv, hb.w, a7);
      }
      if constexpr (PASS == 0) {
        s += (double)a0 + (double)a1 + (double)a2 + (double)a3
           + (double)a4 + (double)a5 + (double)a6 + (double)a7;
        s2 += (double)a0 * a0 + (double)a1 * a1 + (double)a2 * a2 + (double)a3 * a3
            + (double)a4 * a4 + (double)a5 * a5 + (double)a6 * a6 + (double)a7 * a7;
      } else {
        float v;
        v = fmaf(a0, sc3, off3); v = v > 0.f ? v : 0.2f * v; m = fmaxf(m, v);
        v = fmaf(a1, sc3, off3); v = v > 0.f ? v : 0.2f * v; m = fmaxf(m, v);
        v = fmaf(a2, sc3, off3); v = v > 0.f ? v : 0.2f * v; m = fmaxf(m, v);
        v = fmaf(a3, sc3, off3); v = v > 0.f ? v : 0.2f * v; m = fmaxf(m, v);
        v = fmaf(a4, sc3, off3); v = v > 0.f ? v : 0.2f * v; m = fmaxf(m, v);
        v = fmaf(a5, sc3, off3); v = v > 0.f ? v : 0.2f * v; m = fmaxf(m, v);
        v = fmaf(a6, sc3, off3); v = v > 0.f ? v : 0.2f * v; m = fmaxf(m, v);
        v = fmaf(a7, sc3, off3); v = v > 0.f ? v : 0.2f * v; m = fmaxf(m, v);
      }
    }
    if constexpr (PASS == 1) outp[p * OC_ + lane] = m;
  }
  if constexpr (PASS == 0) {
    atomicAdd(&st3[lane], s);
    atomicAdd(&st3[64 + lane], s2);
  }
}

} // namespace

extern "C" void kernel_launch(void* const* d_in, const int* in_sizes, int n_in,
                              void* d_out, int out_size, void* d_ws, size_t ws_size,
                              hipStream_t stream) {
  const float* x   = (const float*)d_in[0];
  const float* pos = (const float*)d_in[1];
  const float* W1  = (const float*)d_in[2];
  const float* g1  = (const float*)d_in[3];
  const float* b1  = (const float*)d_in[4];
  const float* W2  = (const float*)d_in[5];
  const float* g2  = (const float*)d_in[6];
  const float* b2  = (const float*)d_in[7];
  const float* W3  = (const float*)d_in[8];
  const float* g3  = (const float*)d_in[9];
  const float* b3  = (const float*)d_in[10];

  float* outp = (float*)d_out;                 // [B*N*64] float
  float* oidx = outp + B_ * N_ * OC_;          // [B*N*32] idx2 as float values

  char* w = (char*)d_ws;
  double* stats = (double*)w;            w += 640 * sizeof(double);
  float* nxf    = (float*)w;             w += B_ * N_ * 4;
  float* WT1a   = (float*)w;             w += 64 * 128 * 4;
  float* WT1bm  = (float*)w;             w += 64 * 128 * 4;
  float* WT2a   = (float*)w;             w += 128 * 128 * 4;
  float* WT2bm  = (float*)w;             w += 128 * 128 * 4;
  float* W3T    = (float*)w;             w += 128 * 64 * 4;
  float* so1    = (float*)w;             w += 256 * 4;
  float* so2    = (float*)w;             w += 256 * 4;
  float* so3    = (float*)w;             w += 128 * 4;
  int* idx1     = (int*)w;               w += B_ * N_ * K14_ * 4;
  int* idx2i    = (int*)w;               w += B_ * N_ * K2_ * 4;
  bf16* u       = (bf16*)w;              w += B_ * N_ * 128 * 2;
  bf16* uc      = (bf16*)w;              w += B_ * N_ * 128 * 2;
  bf16* h1      = (bf16*)w;              w += B_ * N_ * 128 * 2;
  bf16* zz  = u;    // alias: u dead after h1_kernel
  bf16* zzc = uc;   // alias: uc dead after h1_kernel

  hipMemsetAsync(stats, 0, 640 * sizeof(double), stream);

  xnorm_kernel<<<(B_ * N_ + 255) / 256, 256, 0, stream>>>(x, nxf);
  wprep_kernel<<<64, 256, 0, stream>>>(W1, W2, W3, WT1a, WT1bm, WT2a, WT2bm, W3T);

  knn_x_kernel<<<1024, 512, 0, stream>>>(x, nxf, idx1);
  knn_pos_kernel<<<1024, 512, 0, stream>>>(pos, idx1, idx2i, oidx);

  lin_kernel<64, float><<<2048, 256, 0, stream>>>(x, WT1a, u);
  lin_kernel<64, float><<<2048, 256, 0, stream>>>(x, WT1bm, uc);

  stats_gather_kernel<K14_><<<2048, 256, 0, stream>>>(u, uc, idx1, stats);
  bnfin_kernel<<<1, 128, 0, stream>>>(stats, g1, b1, so1, 128, (double)(B_ * N_ * K14_));
  h1_kernel<<<2048, 256, 0, stream>>>(u, uc, idx1, so1, h1);

  lin_kernel<128, bf16><<<2048, 256, 0, stream>>>(h1, WT2a, zz);
  lin_kernel<128, bf16><<<2048, 256, 0, stream>>>(h1, WT2bm, zzc);

  stats_gather_kernel<K2_><<<2048, 256, 0, stream>>>(zz, zzc, idx2i, stats + 256);
  bnfin_kernel<<<1, 128, 0, stream>>>(stats + 256, g2, b2, so2, 128, (double)(B_ * N_ * K2_));

  conv3_kernel<0><<<2048, 256, 0, stream>>>(zz, zzc, idx2i, so2, nullptr, W3T, stats + 512, nullptr);
  bnfin_kernel<<<1, 128, 0, stream>>>(stats + 512, g3, b3, so3, 64, (double)(B_ * N_ * K2_));
  conv3_kernel<1><<<2048, 256, 0, stream>>>(zz, zzc, idx2i, so2, so3, W3T, nullptr, outp);
}

// Round 9
// 822.121 us; speedup vs baseline: 1.1032x; 1.1032x over previous
//
#include <hip/hip_runtime.h>
#include <hip/hip_bf16.h>
#include <type_traits>

using bf16 = __hip_bfloat16;

namespace {

constexpr int B_ = 2;
constexpr int N_ = 4096;
constexpr int C_ = 64;
constexpr int K14_ = 14;
constexpr int KX_ = 8;
constexpr int KP_ = 6;
constexpr int K2_ = 32;
constexpr int OC_ = 64;

__device__ __forceinline__ float bflo(unsigned u) { return __uint_as_float(u << 16); }
__device__ __forceinline__ float bfhi(unsigned u) { return __uint_as_float(u & 0xffff0000u); }

__device__ __forceinline__ unsigned pack_f16(float a, float b) {
  _Float16 ha = (_Float16)a, hb = (_Float16)b;
  unsigned short ua = __builtin_bit_cast(unsigned short, ha);
  unsigned short ub = __builtin_bit_cast(unsigned short, hb);
  return (unsigned)ua | ((unsigned)ub << 16);
}

using half2v = __attribute__((ext_vector_type(2))) _Float16;
__device__ __forceinline__ float dot2(unsigned a, unsigned b, float acc) {
#if __has_builtin(__builtin_amdgcn_fdot2)
  return __builtin_amdgcn_fdot2(__builtin_bit_cast(half2v, a),
                                __builtin_bit_cast(half2v, b), acc, false);
#else
  half2v ha = __builtin_bit_cast(half2v, a), hb = __builtin_bit_cast(half2v, b);
  acc = fmaf((float)ha[0], (float)hb[0], acc);
  return fmaf((float)ha[1], (float)hb[1], acc);
#endif
}

// monotone u32 key for f32 (no NaN; -0.0 cannot occur for d = t1 - t2 under RN)
__device__ __forceinline__ unsigned fmono(float d) {
  unsigned u = __float_as_uint(d);
  return u ^ (((int)u < 0) ? 0xFFFFFFFFu : 0x80000000u);
}

// Hierarchical per-lane selection: 8 named groups over dst[64] + taken mask.
#define GRP8_ONE(GV, GS, T) \
  { bool av = !((taken >> (T)) & 1ull); bool bb = av && dst[T] < GV; \
    GV = bb ? dst[T] : GV; GS = bb ? (T) : GS; }
#define GRP8(GV, GS, B) do { GV = 3.0e38f; GS = B; \
  GRP8_ONE(GV, GS, (B)+0) GRP8_ONE(GV, GS, (B)+1) GRP8_ONE(GV, GS, (B)+2) \
  GRP8_ONE(GV, GS, (B)+3) GRP8_ONE(GV, GS, (B)+4) GRP8_ONE(GV, GS, (B)+5) \
  GRP8_ONE(GV, GS, (B)+6) GRP8_ONE(GV, GS, (B)+7) } while (0)
#define GTREE_ONE(GV, GS) { bool bb = GV < pv; pv = bb ? GV : pv; ptt = bb ? GS : ptt; }
#define GTREE() do { pv = gv0; ptt = gs0; \
  GTREE_ONE(gv1, gs1) GTREE_ONE(gv2, gs2) GTREE_ONE(gv3, gs3) GTREE_ONE(gv4, gs4) \
  GTREE_ONE(gv5, gs5) GTREE_ONE(gv6, gs6) GTREE_ONE(gv7, gs7) } while (0)
#define GRP_SWITCH(TT) do { switch ((TT) >> 3) { \
  case 0: GRP8(gv0, gs0, 0);  break; case 1: GRP8(gv1, gs1, 8);  break; \
  case 2: GRP8(gv2, gs2, 16); break; case 3: GRP8(gv3, gs3, 24); break; \
  case 4: GRP8(gv4, gs4, 32); break; case 5: GRP8(gv5, gs5, 40); break; \
  case 6: GRP8(gv6, gs6, 48); break; case 7: GRP8(gv7, gs7, 56); break; } \
  GTREE(); } while (0)
#define SEL_DECL float gv0, gv1, gv2, gv3, gv4, gv5, gv6, gv7; \
  int gs0, gs1, gs2, gs3, gs4, gs5, gs6, gs7; float pv; int ptt; \
  unsigned long long taken = 0ull;
#define SEL_INIT do { \
  GRP8(gv0, gs0, 0);  GRP8(gv1, gs1, 8);  GRP8(gv2, gs2, 16); GRP8(gv3, gs3, 24); \
  GRP8(gv4, gs4, 32); GRP8(gv5, gs5, 40); GRP8(gv6, gs6, 48); GRP8(gv7, gs7, 56); \
  GTREE(); } while (0)

// ---------------- x squared norms (f32) ----------------
__global__ __launch_bounds__(256)
void xnorm_kernel(const float* __restrict__ x, float* __restrict__ nx)
{
  int p = blockIdx.x * 256 + threadIdx.x;
  if (p >= B_ * N_) return;
  float s = 0.f;
#pragma unroll 8
  for (int c = 0; c < C_; ++c) { float v = x[p * C_ + c]; s = fmaf(v, v, s); }
  nx[p] = s;
}

// ---------------- weight prep: split + transpose + f16 pack for conv3 ----------
__global__ __launch_bounds__(256)
void wprep_kernel(const float* __restrict__ W1, const float* __restrict__ W2,
                  const float* __restrict__ W3,
                  float* __restrict__ WT1a, float* __restrict__ WT1bm,
                  float* __restrict__ WT2a, float* __restrict__ WT2bm,
                  unsigned* __restrict__ w3p)
{
  int idx = blockIdx.x * 256 + threadIdx.x;
  if (idx < 128 * 128) {
    int o = idx & 127, c = idx >> 7;
    float a = W2[o * 256 + c];
    WT2a[c * 128 + o] = a;
    WT2bm[c * 128 + o] = W2[o * 256 + 128 + c] - a;
    if (c < 64) {
      float a1 = W1[o * 128 + c];
      WT1a[c * 128 + o] = a1;
      WT1bm[c * 128 + o] = W1[o * 128 + 64 + c] - a1;
    }
  }
  if (idx < 64 * 64) {
    int oo = idx & 63, c2 = idx >> 6;
    w3p[c2 * 64 + oo] = pack_f16(W3[oo * 128 + 2 * c2], W3[oo * 128 + 2 * c2 + 1]);
  }
}

// ---------------- knn over x v4: f16 dot2, q in SGPRs, conflict-free b32 LDS ----
__global__ __launch_bounds__(512, 4)
void knn_x_kernel(const float* __restrict__ x, const float* __restrict__ nx,
                  int* __restrict__ idx1)
{
  __shared__ unsigned tileh[256 * 33];     // 33 KB
  const int wave = threadIdx.x >> 6, lane = threadIdx.x & 63;
  const int qg = blockIdx.x * 8 + wave;    // 1024 blocks * 8 waves
  const int bb = qg >> 12;
  const float* xb = x + bb * N_ * C_;
  unsigned myq;
  {
    float2 qv = *(const float2*)&x[qg * C_ + 2 * (lane & 31)];
    myq = pack_f16(qv.x, qv.y);
  }
  unsigned qp[32];
#pragma unroll
  for (int c2 = 0; c2 < 32; ++c2) qp[c2] = __builtin_amdgcn_readlane(myq, c2);
  const float nq = nx[qg];
  const float* nb_ = nx + bb * N_;
  float dst[64];
#pragma unroll
  for (int ti = 0; ti < 16; ++ti) {
    __syncthreads();
    for (int e = threadIdx.x; e < 256 * 32; e += 512) {
      int c2 = e & 31, j = e >> 5;
      float2 v = *(const float2*)&xb[(ti * 256 + j) * C_ + 2 * c2];
      tileh[j * 33 + c2] = pack_f16(v.x, v.y);
    }
    __syncthreads();
#pragma unroll
    for (int nb4 = 0; nb4 < 4; ++nb4) {
      const unsigned* row = &tileh[(nb4 * 64 + lane) * 33];
      float acc = 0.f;
#pragma unroll
      for (int c2 = 0; c2 < 32; ++c2) acc = dot2(qp[c2], row[c2], acc);
      float nbv = nb_[ti * 256 + nb4 * 64 + lane];
      dst[ti * 4 + nb4] = nq + nbv - 2.f * acc;
    }
  }
  SEL_DECL;
  SEL_INIT;
  for (int r = 0; r < KX_ + 1; ++r) {
    int j = ((ptt >> 2) << 8) + ((ptt & 3) << 6) + lane;
    unsigned long long key = ((unsigned long long)fmono(pv) << 32) | (unsigned)j;
#pragma unroll
    for (int m = 1; m < 64; m <<= 1) {
      unsigned long long ok = __shfl_xor(key, m, 64);
      key = ok < key ? ok : key;
    }
    int wj = (int)(key & 0xFFFFFFFFull);
    if (r > 0 && lane == 0) idx1[qg * K14_ + (r - 1)] = wj;
    if ((wj & 63) == lane) {
      int tt = ((wj >> 8) << 2) | ((wj >> 6) & 3);
      taken |= 1ull << tt;
      GRP_SWITCH(tt);
    }
  }
}

// ---------------- knn over pos: bit-exact numpy-f32 distances (graded idx2) -----
__global__ __launch_bounds__(512, 2)
void knn_pos_kernel(const float* __restrict__ pos,
                    int* __restrict__ idx1, int* __restrict__ idx2,
                    float* __restrict__ oidx)
{
#pragma clang fp contract(off)
  __shared__ float pL[3][N_];
  __shared__ float nL[N_];
  const int wave = threadIdx.x >> 6, lane = threadIdx.x & 63;
  const int qg = blockIdx.x * 8 + wave;
  const int bb = qg >> 12;
  const float* pb = pos + bb * N_ * 3;
  for (int j = threadIdx.x; j < N_; j += 512) {
    float a = pb[j * 3], b = pb[j * 3 + 1], c = pb[j * 3 + 2];
    pL[0][j] = a; pL[1][j] = b; pL[2][j] = c;
    float aa = a * a;
    float bb2 = b * b;
    float cc = c * c;
    float s1 = aa + bb2;
    nL[j] = s1 + cc;
  }
  __syncthreads();
  const int q = qg & (N_ - 1);
  const float qx = pL[0][q], qy = pL[1][q], qz = pL[2][q];
  const float nq = nL[q];
  float dst[64];
#pragma unroll
  for (int t = 0; t < 64; ++t) {
    int j = t * 64 + lane;
    float dot = qx * pL[0][j];
    dot = fmaf(qy, pL[1][j], dot);
    dot = fmaf(qz, pL[2][j], dot);
    float t1 = nq + nL[j];
    float t2 = 2.0f * dot;
    dst[t] = t1 - t2;
  }
  SEL_DECL;
  SEL_INIT;
  for (int r = 0; r < K2_ + 1; ++r) {
    int j = ptt * 64 + lane;
    unsigned long long key = ((unsigned long long)fmono(pv) << 32) | (unsigned)j;
#pragma unroll
    for (int m = 1; m < 64; m <<= 1) {
      unsigned long long ok = __shfl_xor(key, m, 64);
      key = ok < key ? ok : key;
    }
    int wj = (int)(key & 0xFFFFFFFFull);
    if (r > 0 && lane == 0) {
      int rr = r - 1;
      if (rr < KP_) idx1[qg * K14_ + KX_ + rr] = wj;
      idx2[qg * K2_ + rr] = wj;
      oidx[qg * K2_ + rr] = (float)wj;
    }
    if ((wj & 63) == lane) {
      int tt = wj >> 6;
      taken |= 1ull << tt;
      GRP_SWITCH(tt);
    }
  }
}

// ---------------- per-point projection ----------------
template<int CIN, typename TIN>
__global__ __launch_bounds__(256)
void lin_kernel(const TIN* __restrict__ in, const float* __restrict__ WT,
                bf16* __restrict__ out)
{
  __shared__ float wt[CIN * 128];
  for (int e = threadIdx.x; e < CIN * 128; e += 256) wt[e] = WT[e];
  __syncthreads();
  const int which = threadIdx.x >> 7, o = threadIdx.x & 127;
  for (int p0 = blockIdx.x * 2; p0 < B_ * N_; p0 += gridDim.x * 2) {
    int p = p0 + which;
    float acc = 0.f;
#pragma unroll 8
    for (int c = 0; c < CIN; ++c) {
      float v;
      if constexpr (std::is_same_v<TIN, float>) v = in[p * CIN + c];
      else v = __bfloat162float(in[p * CIN + c]);
      acc = fmaf(wt[c * 128 + o], v, acc);
    }
    out[p * 128 + o] = __float2bfloat16(acc);
  }
}

// ---------------- BN stats over gathered y = a[nbr] + ac[ctr], p-major ---------
template<int KNB>
__global__ __launch_bounds__(256)
void stats_gather_kernel(const bf16* __restrict__ a, const bf16* __restrict__ ac,
                         const int* __restrict__ nbr, double* __restrict__ st)
{
  const int o = threadIdx.x & 127;
  const int which = threadIdx.x >> 7;
  double s = 0.0, s2 = 0.0;
  for (int p0 = blockIdx.x * 2; p0 < B_ * N_; p0 += gridDim.x * 2) {
    int p = p0 + which;
    int base = (p >> 12) << 12;
    float acv = __bfloat162float(ac[p * 128 + o]);
#pragma unroll 2
    for (int kk = 0; kk < KNB; ++kk) {
      int nb = nbr[p * KNB + kk] & (N_ - 1);
      float y = __bfloat162float(a[(base + nb) * 128 + o]) + acv;
      s += (double)y; s2 += (double)y * (double)y;
    }
  }
  atomicAdd(&st[o], s);
  atomicAdd(&st[128 + o], s2);
}

// ---------------- BN finalize ----------------
__global__ void bnfin_kernel(const double* __restrict__ st, const float* __restrict__ g,
                             const float* __restrict__ bi, float* __restrict__ so,
                             int nch, double cnt)
{
  int o = threadIdx.x;
  if (o >= nch) return;
  double mu = st[o] / cnt;
  double var = st[nch + o] / cnt - mu * mu;
  double sc = (double)g[o] / sqrt(var + 1e-5);
  so[o] = (float)sc;
  so[nch + o] = (float)((double)bi[o] - mu * sc);
}

// ---------------- h1 = max_k lrelu(bn(u[nbr]+uc[ctr])) ----------------
__global__ __launch_bounds__(256)
void h1_kernel(const bf16* __restrict__ u, const bf16* __restrict__ uc,
               const int* __restrict__ idx1, const float* __restrict__ so,
               bf16* __restrict__ h1)
{
  const int o = threadIdx.x & 127, which = threadIdx.x >> 7;
  float sc = so[o], off = so[128 + o];
  for (int p0 = blockIdx.x * 2; p0 < B_ * N_; p0 += gridDim.x * 2) {
    int p = p0 + which;
    int base = (p >> 12) << 12;
    float ucv = __bfloat162float(uc[p * 128 + o]);
    float m = -3.0e38f;
#pragma unroll
    for (int kk = 0; kk < K14_; ++kk) {
      int nb = idx1[p * K14_ + kk] & (N_ - 1);
      float y = __bfloat162float(u[(base + nb) * 128 + o]) + ucv;
      float v = fmaf(y, sc, off);
      v = v > 0.f ? v : 0.2f * v;
      m = fmaxf(m, v);
    }
    h1[p * 128 + o] = __float2bfloat16(m);
  }
}

// ---------------- conv3 v2: f16 dot2 matvec, 24KB LDS, swizzled h2p ------------
// Per wave per point: 4 chunks of 8 edges. Lane = output channel oo.
// h2p layout: [c2][i^swz(c2)] with swz(c2)=(c2>>2)&7 -> conflict-free writes,
// 2x b128 broadcast reads; permutation undone with compile-time indices.
template<int PASS>
__global__ __launch_bounds__(256, 5)
void conv3_kernel(const bf16* __restrict__ z, const bf16* __restrict__ zc,
                  const int* __restrict__ idx2, const float* __restrict__ so2,
                  const float* __restrict__ so3, const unsigned* __restrict__ w3p,
                  double* __restrict__ st3, float* __restrict__ outp)
{
  __shared__ unsigned w3s[64 * 64];      // 16 KB [c2][oo] f16 pairs
  __shared__ unsigned h2s[4][512];       // 8 KB: per-wave [c2][8]
  {
    const uint4* src = (const uint4*)w3p;
    uint4* dst4 = (uint4*)w3s;
    for (int e = threadIdx.x; e < 1024; e += 256) dst4[e] = src[e];
  }
  __syncthreads();
  const int wave = threadIdx.x >> 6, lane = threadIdx.x & 63;
  unsigned* h2w = &h2s[wave][0];
  const int swz = (lane >> 2) & 7;
  const float sclo = so2[2 * lane],       schi = so2[2 * lane + 1];
  const float offlo = so2[128 + 2 * lane], offhi = so2[129 + 2 * lane];
  float sc3 = 0.f, off3 = 0.f;
  if constexpr (PASS == 1) { sc3 = so3[lane]; off3 = so3[64 + lane]; }
  double s = 0.0, s2 = 0.0;
  const int gw = blockIdx.x * 4 + wave;
  const int stride = gridDim.x * 4;
  for (int p = gw; p < B_ * N_; p += stride) {
    const int base = (p >> 12) << 12;
    const unsigned zcv = *(const unsigned*)&zc[p * 128 + 2 * lane];
    const float zclo = bflo(zcv), zchi = bfhi(zcv);
    float m = -3.0e38f;
#pragma unroll
    for (int kc = 0; kc < 4; ++kc) {
      asm volatile("s_waitcnt lgkmcnt(0)" ::: "memory");   // WAR vs prev chunk reads
#pragma unroll
      for (int i = 0; i < 8; ++i) {
        int nb = idx2[p * K2_ + kc * 8 + i] & (N_ - 1);
        unsigned zv = *(const unsigned*)&z[(base + nb) * 128 + 2 * lane];
        float y0 = bflo(zv) + zclo;
        float y1 = bfhi(zv) + zchi;
        float v0 = fmaf(y0, sclo, offlo); v0 = v0 > 0.f ? v0 : 0.2f * v0;
        float v1 = fmaf(y1, schi, offhi); v1 = v1 > 0.f ? v1 : 0.2f * v1;
        h2w[(lane << 3) | (i ^ swz)] = pack_f16(v0, v1);
      }
      asm volatile("s_waitcnt lgkmcnt(0)" ::: "memory");   // RAW: writes visible
      float a0 = 0.f, a1 = 0.f, a2 = 0.f, a3 = 0.f;
      float a4 = 0.f, a5 = 0.f, a6 = 0.f, a7 = 0.f;
#pragma unroll
      for (int c2 = 0; c2 < 64; ++c2) {
        const int cs = (c2 >> 2) & 7;              // constant after unroll
        unsigned wp = w3s[(c2 << 6) | lane];
        uint4 ra = *(const uint4*)&h2w[c2 << 3];
        uint4 rb = *(const uint4*)&h2w[(c2 << 3) + 4];
        unsigned hv[8] = {ra.x, ra.y, ra.z, ra.w, rb.x, rb.y, rb.z, rb.w};
        a0 = dot2(wp, hv[0 ^ cs], a0);
        a1 = dot2(wp, hv[1 ^ cs], a1);
        a2 = dot2(wp, hv[2 ^ cs], a2);
        a3 = dot2(wp, hv[3 ^ cs], a3);
        a4 = dot2(wp, hv[4 ^ cs], a4);
        a5 = dot2(wp, hv[5 ^ cs], a5);
        a6 = dot2(wp, hv[6 ^ cs], a6);
        a7 = dot2(wp, hv[7 ^ cs], a7);
      }
      if constexpr (PASS == 0) {
        s += (double)a0 + (double)a1 + (double)a2 + (double)a3
           + (double)a4 + (double)a5 + (double)a6 + (double)a7;
        s2 += (double)a0 * a0 + (double)a1 * a1 + (double)a2 * a2 + (double)a3 * a3
            + (double)a4 * a4 + (double)a5 * a5 + (double)a6 * a6 + (double)a7 * a7;
      } else {
        float v;
        v = fmaf(a0, sc3, off3); v = v > 0.f ? v : 0.2f * v; m = fmaxf(m, v);
        v = fmaf(a1, sc3, off3); v = v > 0.f ? v : 0.2f * v; m = fmaxf(m, v);
        v = fmaf(a2, sc3, off3); v = v > 0.f ? v : 0.2f * v; m = fmaxf(m, v);
        v = fmaf(a3, sc3, off3); v = v > 0.f ? v : 0.2f * v; m = fmaxf(m, v);
        v = fmaf(a4, sc3, off3); v = v > 0.f ? v : 0.2f * v; m = fmaxf(m, v);
        v = fmaf(a5, sc3, off3); v = v > 0.f ? v : 0.2f * v; m = fmaxf(m, v);
        v = fmaf(a6, sc3, off3); v = v > 0.f ? v : 0.2f * v; m = fmaxf(m, v);
        v = fmaf(a7, sc3, off3); v = v > 0.f ? v : 0.2f * v; m = fmaxf(m, v);
      }
    }
    if constexpr (PASS == 1) outp[p * OC_ + lane] = m;
  }
  if constexpr (PASS == 0) {
    atomicAdd(&st3[lane], s);
    atomicAdd(&st3[64 + lane], s2);
  }
}

} // namespace

extern "C" void kernel_launch(void* const* d_in, const int* in_sizes, int n_in,
                              void* d_out, int out_size, void* d_ws, size_t ws_size,
                              hipStream_t stream) {
  const float* x   = (const float*)d_in[0];
  const float* pos = (const float*)d_in[1];
  const float* W1  = (const float*)d_in[2];
  const float* g1  = (const float*)d_in[3];
  const float* b1  = (const float*)d_in[4];
  const float* W2  = (const float*)d_in[5];
  const float* g2  = (const float*)d_in[6];
  const float* b2  = (const float*)d_in[7];
  const float* W3  = (const float*)d_in[8];
  const float* g3  = (const float*)d_in[9];
  const float* b3  = (const float*)d_in[10];

  float* outp = (float*)d_out;                 // [B*N*64] float
  float* oidx = outp + B_ * N_ * OC_;          // [B*N*32] idx2 as float values

  char* w = (char*)d_ws;
  double* stats = (double*)w;            w += 640 * sizeof(double);
  float* nxf    = (float*)w;             w += B_ * N_ * 4;
  float* WT1a   = (float*)w;             w += 64 * 128 * 4;
  float* WT1bm  = (float*)w;             w += 64 * 128 * 4;
  float* WT2a   = (float*)w;             w += 128 * 128 * 4;
  float* WT2bm  = (float*)w;             w += 128 * 128 * 4;
  unsigned* w3p = (unsigned*)w;          w += 64 * 64 * 4;
  float* so1    = (float*)w;             w += 256 * 4;
  float* so2    = (float*)w;             w += 256 * 4;
  float* so3    = (float*)w;             w += 128 * 4;
  int* idx1     = (int*)w;               w += B_ * N_ * K14_ * 4;
  int* idx2i    = (int*)w;               w += B_ * N_ * K2_ * 4;
  bf16* u       = (bf16*)w;              w += B_ * N_ * 128 * 2;
  bf16* uc      = (bf16*)w;              w += B_ * N_ * 128 * 2;
  bf16* h1      = (bf16*)w;              w += B_ * N_ * 128 * 2;
  bf16* zz  = u;    // alias: u dead after h1_kernel
  bf16* zzc = uc;   // alias: uc dead after h1_kernel

  hipMemsetAsync(stats, 0, 640 * sizeof(double), stream);

  xnorm_kernel<<<(B_ * N_ + 255) / 256, 256, 0, stream>>>(x, nxf);
  wprep_kernel<<<64, 256, 0, stream>>>(W1, W2, W3, WT1a, WT1bm, WT2a, WT2bm, w3p);

  knn_x_kernel<<<1024, 512, 0, stream>>>(x, nxf, idx1);
  knn_pos_kernel<<<1024, 512, 0, stream>>>(pos, idx1, idx2i, oidx);

  lin_kernel<64, float><<<2048, 256, 0, stream>>>(x, WT1a, u);
  lin_kernel<64, float><<<2048, 256, 0, stream>>>(x, WT1bm, uc);

  stats_gather_kernel<K14_><<<2048, 256, 0, stream>>>(u, uc, idx1, stats);
  bnfin_kernel<<<1, 128, 0, stream>>>(stats, g1, b1, so1, 128, (double)(B_ * N_ * K14_));
  h1_kernel<<<2048, 256, 0, stream>>>(u, uc, idx1, so1, h1);

  lin_kernel<128, bf16><<<2048, 256, 0, stream>>>(h1, WT2a, zz);
  lin_kernel<128, bf16><<<2048, 256, 0, stream>>>(h1, WT2bm, zzc);

  stats_gather_kernel<K2_><<<2048, 256, 0, stream>>>(zz, zzc, idx2i, stats + 256);
  bnfin_kernel<<<1, 128, 0, stream>>>(stats + 256, g2, b2, so2, 128, (double)(B_ * N_ * K2_));

  conv3_kernel<0><<<2048, 256, 0, stream>>>(zz, zzc, idx2i, so2, nullptr, w3p, stats + 512, nullptr);
  bnfin_kernel<<<1, 128, 0, stream>>>(stats + 512, g3, b3, so3, 64, (double)(B_ * N_ * K2_));
  conv3_kernel<1><<<2048, 256, 0, stream>>>(zz, zzc, idx2i, so2, so3, w3p, nullptr, outp);
}

// Round 10
// 698.593 us; speedup vs baseline: 1.2983x; 1.1768x over previous
//
#include <hip/hip_runtime.h>
#include <hip/hip_bf16.h>
#include <type_traits>

using bf16 = __hip_bfloat16;

namespace {

constexpr int B_ = 2;
constexpr int N_ = 4096;
constexpr int C_ = 64;
constexpr int K14_ = 14;
constexpr int KX_ = 8;
constexpr int KP_ = 6;
constexpr int K2_ = 32;
constexpr int OC_ = 64;

__device__ __forceinline__ float bflo(unsigned u) { return __uint_as_float(u << 16); }
__device__ __forceinline__ float bfhi(unsigned u) { return __uint_as_float(u & 0xffff0000u); }

__device__ __forceinline__ unsigned pack_f16(float a, float b) {
  _Float16 ha = (_Float16)a, hb = (_Float16)b;
  unsigned short ua = __builtin_bit_cast(unsigned short, ha);
  unsigned short ub = __builtin_bit_cast(unsigned short, hb);
  return (unsigned)ua | ((unsigned)ub << 16);
}

using half2v = __attribute__((ext_vector_type(2))) _Float16;
__device__ __forceinline__ float dot2(unsigned a, unsigned b, float acc) {
#if __has_builtin(__builtin_amdgcn_fdot2)
  return __builtin_amdgcn_fdot2(__builtin_bit_cast(half2v, a),
                                __builtin_bit_cast(half2v, b), acc, false);
#else
  half2v ha = __builtin_bit_cast(half2v, a), hb = __builtin_bit_cast(half2v, b);
  acc = fmaf((float)ha[0], (float)hb[0], acc);
  return fmaf((float)ha[1], (float)hb[1], acc);
#endif
}

// monotone u32 key for f32 (no NaN; -0.0 cannot occur for d = t1 - t2 under RN)
__device__ __forceinline__ unsigned fmono(float d) {
  unsigned u = __float_as_uint(d);
  return u ^ (((int)u < 0) ? 0xFFFFFFFFu : 0x80000000u);
}

// Hierarchical per-lane selection: 8 named groups over dst[64] + taken mask.
#define GRP8_ONE(GV, GS, T) \
  { bool av = !((taken >> (T)) & 1ull); bool bb = av && dst[T] < GV; \
    GV = bb ? dst[T] : GV; GS = bb ? (T) : GS; }
#define GRP8(GV, GS, B) do { GV = 3.0e38f; GS = B; \
  GRP8_ONE(GV, GS, (B)+0) GRP8_ONE(GV, GS, (B)+1) GRP8_ONE(GV, GS, (B)+2) \
  GRP8_ONE(GV, GS, (B)+3) GRP8_ONE(GV, GS, (B)+4) GRP8_ONE(GV, GS, (B)+5) \
  GRP8_ONE(GV, GS, (B)+6) GRP8_ONE(GV, GS, (B)+7) } while (0)
#define GTREE_ONE(GV, GS) { bool bb = GV < pv; pv = bb ? GV : pv; ptt = bb ? GS : ptt; }
#define GTREE() do { pv = gv0; ptt = gs0; \
  GTREE_ONE(gv1, gs1) GTREE_ONE(gv2, gs2) GTREE_ONE(gv3, gs3) GTREE_ONE(gv4, gs4) \
  GTREE_ONE(gv5, gs5) GTREE_ONE(gv6, gs6) GTREE_ONE(gv7, gs7) } while (0)
#define GRP_SWITCH(TT) do { switch ((TT) >> 3) { \
  case 0: GRP8(gv0, gs0, 0);  break; case 1: GRP8(gv1, gs1, 8);  break; \
  case 2: GRP8(gv2, gs2, 16); break; case 3: GRP8(gv3, gs3, 24); break; \
  case 4: GRP8(gv4, gs4, 32); break; case 5: GRP8(gv5, gs5, 40); break; \
  case 6: GRP8(gv6, gs6, 48); break; case 7: GRP8(gv7, gs7, 56); break; } \
  GTREE(); } while (0)
#define SEL_DECL float gv0, gv1, gv2, gv3, gv4, gv5, gv6, gv7; \
  int gs0, gs1, gs2, gs3, gs4, gs5, gs6, gs7; float pv; int ptt; \
  unsigned long long taken = 0ull;
#define SEL_INIT do { \
  GRP8(gv0, gs0, 0);  GRP8(gv1, gs1, 8);  GRP8(gv2, gs2, 16); GRP8(gv3, gs3, 24); \
  GRP8(gv4, gs4, 32); GRP8(gv5, gs5, 40); GRP8(gv6, gs6, 48); GRP8(gv7, gs7, 56); \
  GTREE(); } while (0)

// ---------------- x squared norms (f32) ----------------
__global__ __launch_bounds__(256)
void xnorm_kernel(const float* __restrict__ x, float* __restrict__ nx)
{
  int p = blockIdx.x * 256 + threadIdx.x;
  if (p >= B_ * N_) return;
  float s = 0.f;
#pragma unroll 8
  for (int c = 0; c < C_; ++c) { float v = x[p * C_ + c]; s = fmaf(v, v, s); }
  nx[p] = s;
}

// ---------------- weight prep: split + transpose + f16 pack for conv3 ----------
__global__ __launch_bounds__(256)
void wprep_kernel(const float* __restrict__ W1, const float* __restrict__ W2,
                  const float* __restrict__ W3,
                  float* __restrict__ WT1a, float* __restrict__ WT1bm,
                  float* __restrict__ WT2a, float* __restrict__ WT2bm,
                  unsigned* __restrict__ w3p)
{
  int idx = blockIdx.x * 256 + threadIdx.x;
  if (idx < 128 * 128) {
    int o = idx & 127, c = idx >> 7;
    float a = W2[o * 256 + c];
    WT2a[c * 128 + o] = a;
    WT2bm[c * 128 + o] = W2[o * 256 + 128 + c] - a;
    if (c < 64) {
      float a1 = W1[o * 128 + c];
      WT1a[c * 128 + o] = a1;
      WT1bm[c * 128 + o] = W1[o * 128 + 64 + c] - a1;
    }
  }
  if (idx < 64 * 64) {
    int oo = idx & 63, c2 = idx >> 6;
    w3p[c2 * 64 + oo] = pack_f16(W3[oo * 128 + 2 * c2], W3[oo * 128 + 2 * c2 + 1]);
  }
}

// ---------------- knn over x v4: f16 dot2, q in SGPRs, conflict-free b32 LDS ----
__global__ __launch_bounds__(512, 4)
void knn_x_kernel(const float* __restrict__ x, const float* __restrict__ nx,
                  int* __restrict__ idx1)
{
  __shared__ unsigned tileh[256 * 33];     // 33 KB
  const int wave = threadIdx.x >> 6, lane = threadIdx.x & 63;
  const int qg = blockIdx.x * 8 + wave;    // 1024 blocks * 8 waves
  const int bb = qg >> 12;
  const float* xb = x + bb * N_ * C_;
  unsigned myq;
  {
    float2 qv = *(const float2*)&x[qg * C_ + 2 * (lane & 31)];
    myq = pack_f16(qv.x, qv.y);
  }
  unsigned qp[32];
#pragma unroll
  for (int c2 = 0; c2 < 32; ++c2) qp[c2] = __builtin_amdgcn_readlane(myq, c2);
  const float nq = nx[qg];
  const float* nb_ = nx + bb * N_;
  float dst[64];
#pragma unroll
  for (int ti = 0; ti < 16; ++ti) {
    __syncthreads();
    for (int e = threadIdx.x; e < 256 * 32; e += 512) {
      int c2 = e & 31, j = e >> 5;
      float2 v = *(const float2*)&xb[(ti * 256 + j) * C_ + 2 * c2];
      tileh[j * 33 + c2] = pack_f16(v.x, v.y);
    }
    __syncthreads();
#pragma unroll
    for (int nb4 = 0; nb4 < 4; ++nb4) {
      const unsigned* row = &tileh[(nb4 * 64 + lane) * 33];
      float acc = 0.f;
#pragma unroll
      for (int c2 = 0; c2 < 32; ++c2) acc = dot2(qp[c2], row[c2], acc);
      float nbv = nb_[ti * 256 + nb4 * 64 + lane];
      dst[ti * 4 + nb4] = nq + nbv - 2.f * acc;
    }
  }
  SEL_DECL;
  SEL_INIT;
  for (int r = 0; r < KX_ + 1; ++r) {
    int j = ((ptt >> 2) << 8) + ((ptt & 3) << 6) + lane;
    unsigned long long key = ((unsigned long long)fmono(pv) << 32) | (unsigned)j;
#pragma unroll
    for (int m = 1; m < 64; m <<= 1) {
      unsigned long long ok = __shfl_xor(key, m, 64);
      key = ok < key ? ok : key;
    }
    int wj = (int)(key & 0xFFFFFFFFull);
    if (r > 0 && lane == 0) idx1[qg * K14_ + (r - 1)] = wj;
    if ((wj & 63) == lane) {
      int tt = ((wj >> 8) << 2) | ((wj >> 6) & 3);
      taken |= 1ull << tt;
      GRP_SWITCH(tt);
    }
  }
}

// ---------------- knn over pos: bit-exact numpy-f32 distances (graded idx2) -----
__global__ __launch_bounds__(512, 2)
void knn_pos_kernel(const float* __restrict__ pos,
                    int* __restrict__ idx1, int* __restrict__ idx2,
                    float* __restrict__ oidx)
{
#pragma clang fp contract(off)
  __shared__ float pL[3][N_];
  __shared__ float nL[N_];
  const int wave = threadIdx.x >> 6, lane = threadIdx.x & 63;
  const int qg = blockIdx.x * 8 + wave;
  const int bb = qg >> 12;
  const float* pb = pos + bb * N_ * 3;
  for (int j = threadIdx.x; j < N_; j += 512) {
    float a = pb[j * 3], b = pb[j * 3 + 1], c = pb[j * 3 + 2];
    pL[0][j] = a; pL[1][j] = b; pL[2][j] = c;
    float aa = a * a;
    float bb2 = b * b;
    float cc = c * c;
    float s1 = aa + bb2;
    nL[j] = s1 + cc;
  }
  __syncthreads();
  const int q = qg & (N_ - 1);
  const float qx = pL[0][q], qy = pL[1][q], qz = pL[2][q];
  const float nq = nL[q];
  float dst[64];
#pragma unroll
  for (int t = 0; t < 64; ++t) {
    int j = t * 64 + lane;
    float dot = qx * pL[0][j];
    dot = fmaf(qy, pL[1][j], dot);
    dot = fmaf(qz, pL[2][j], dot);
    float t1 = nq + nL[j];
    float t2 = 2.0f * dot;
    dst[t] = t1 - t2;
  }
  SEL_DECL;
  SEL_INIT;
  for (int r = 0; r < K2_ + 1; ++r) {
    int j = ptt * 64 + lane;
    unsigned long long key = ((unsigned long long)fmono(pv) << 32) | (unsigned)j;
#pragma unroll
    for (int m = 1; m < 64; m <<= 1) {
      unsigned long long ok = __shfl_xor(key, m, 64);
      key = ok < key ? ok : key;
    }
    int wj = (int)(key & 0xFFFFFFFFull);
    if (r > 0 && lane == 0) {
      int rr = r - 1;
      if (rr < KP_) idx1[qg * K14_ + KX_ + rr] = wj;
      idx2[qg * K2_ + rr] = wj;
      oidx[qg * K2_ + rr] = (float)wj;
    }
    if ((wj & 63) == lane) {
      int tt = wj >> 6;
      taken |= 1ull << tt;
      GRP_SWITCH(tt);
    }
  }
}

// ---------------- per-point projection ----------------
template<int CIN, typename TIN>
__global__ __launch_bounds__(256)
void lin_kernel(const TIN* __restrict__ in, const float* __restrict__ WT,
                bf16* __restrict__ out)
{
  __shared__ float wt[CIN * 128];
  for (int e = threadIdx.x; e < CIN * 128; e += 256) wt[e] = WT[e];
  __syncthreads();
  const int which = threadIdx.x >> 7, o = threadIdx.x & 127;
  for (int p0 = blockIdx.x * 2; p0 < B_ * N_; p0 += gridDim.x * 2) {
    int p = p0 + which;
    float acc = 0.f;
#pragma unroll 8
    for (int c = 0; c < CIN; ++c) {
      float v;
      if constexpr (std::is_same_v<TIN, float>) v = in[p * CIN + c];
      else v = __bfloat162float(in[p * CIN + c]);
      acc = fmaf(wt[c * 128 + o], v, acc);
    }
    out[p * 128 + o] = __float2bfloat16(acc);
  }
}

// ---------------- BN stats over gathered y = a[nbr] + ac[ctr], p-major ---------
template<int KNB>
__global__ __launch_bounds__(256)
void stats_gather_kernel(const bf16* __restrict__ a, const bf16* __restrict__ ac,
                         const int* __restrict__ nbr, double* __restrict__ st)
{
  const int o = threadIdx.x & 127;
  const int which = threadIdx.x >> 7;
  double s = 0.0, s2 = 0.0;
  for (int p0 = blockIdx.x * 2; p0 < B_ * N_; p0 += gridDim.x * 2) {
    int p = p0 + which;
    int base = (p >> 12) << 12;
    float acv = __bfloat162float(ac[p * 128 + o]);
#pragma unroll 2
    for (int kk = 0; kk < KNB; ++kk) {
      int nb = nbr[p * KNB + kk] & (N_ - 1);
      float y = __bfloat162float(a[(base + nb) * 128 + o]) + acv;
      s += (double)y; s2 += (double)y * (double)y;
    }
  }
  atomicAdd(&st[o], s);
  atomicAdd(&st[128 + o], s2);
}

// ---------------- BN finalize ----------------
__global__ void bnfin_kernel(const double* __restrict__ st, const float* __restrict__ g,
                             const float* __restrict__ bi, float* __restrict__ so,
                             int nch, double cnt)
{
  int o = threadIdx.x;
  if (o >= nch) return;
  double mu = st[o] / cnt;
  double var = st[nch + o] / cnt - mu * mu;
  double sc = (double)g[o] / sqrt(var + 1e-5);
  so[o] = (float)sc;
  so[nch + o] = (float)((double)bi[o] - mu * sc);
}

// ---------------- h1 = max_k lrelu(bn(u[nbr]+uc[ctr])) ----------------
__global__ __launch_bounds__(256)
void h1_kernel(const bf16* __restrict__ u, const bf16* __restrict__ uc,
               const int* __restrict__ idx1, const float* __restrict__ so,
               bf16* __restrict__ h1)
{
  const int o = threadIdx.x & 127, which = threadIdx.x >> 7;
  float sc = so[o], off = so[128 + o];
  for (int p0 = blockIdx.x * 2; p0 < B_ * N_; p0 += gridDim.x * 2) {
    int p = p0 + which;
    int base = (p >> 12) << 12;
    float ucv = __bfloat162float(uc[p * 128 + o]);
    float m = -3.0e38f;
#pragma unroll
    for (int kk = 0; kk < K14_; ++kk) {
      int nb = idx1[p * K14_ + kk] & (N_ - 1);
      float y = __bfloat162float(u[(base + nb) * 128 + o]) + ucv;
      float v = fmaf(y, sc, off);
      v = v > 0.f ? v : 0.2f * v;
      m = fmaxf(m, v);
    }
    h1[p * 128 + o] = __float2bfloat16(m);
  }
}

// ---------------- conv3 stats+minmax: single gather/matvec pass ----------------
// Computes BN3 stats AND per-(point,oo) y3 max/min (f16 pair). The final output
// is then lrelu(sc3*(sc3>=0?max:min)+off3) — exact since lrelu/affine monotone.
__global__ __launch_bounds__(256, 5)
void conv3s_kernel(const bf16* __restrict__ z, const bf16* __restrict__ zc,
                   const int* __restrict__ idx2, const float* __restrict__ so2,
                   const unsigned* __restrict__ w3p,
                   double* __restrict__ st3, unsigned* __restrict__ y3m)
{
  __shared__ unsigned w3s[64 * 64];      // 16 KB [c2][oo] f16 pairs
  __shared__ unsigned h2s[4][512];       // 8 KB: per-wave [c2][8]
  {
    const uint4* src = (const uint4*)w3p;
    uint4* dst4 = (uint4*)w3s;
    for (int e = threadIdx.x; e < 1024; e += 256) dst4[e] = src[e];
  }
  __syncthreads();
  const int wave = threadIdx.x >> 6, lane = threadIdx.x & 63;
  unsigned* h2w = &h2s[wave][0];
  const int swz = (lane >> 2) & 7;
  const float sclo = so2[2 * lane],       schi = so2[2 * lane + 1];
  const float offlo = so2[128 + 2 * lane], offhi = so2[129 + 2 * lane];
  double s = 0.0, s2 = 0.0;
  const int gw = blockIdx.x * 4 + wave;       // 1024 blocks -> 4096 waves, 2 pts/wave
  const int stride = gridDim.x * 4;
  for (int p = gw; p < B_ * N_; p += stride) {
    const int base = (p >> 12) << 12;
    const unsigned zcv = *(const unsigned*)&zc[p * 128 + 2 * lane];
    const float zclo = bflo(zcv), zchi = bfhi(zcv);
    float mx = -3.0e38f, mn = 3.0e38f;
#pragma unroll
    for (int kc = 0; kc < 4; ++kc) {
      asm volatile("s_waitcnt lgkmcnt(0)" ::: "memory");   // WAR vs prev chunk reads
#pragma unroll
      for (int i = 0; i < 8; ++i) {
        int nb = idx2[p * K2_ + kc * 8 + i] & (N_ - 1);
        unsigned zv = *(const unsigned*)&z[(base + nb) * 128 + 2 * lane];
        float y0 = bflo(zv) + zclo;
        float y1 = bfhi(zv) + zchi;
        float v0 = fmaf(y0, sclo, offlo); v0 = v0 > 0.f ? v0 : 0.2f * v0;
        float v1 = fmaf(y1, schi, offhi); v1 = v1 > 0.f ? v1 : 0.2f * v1;
        h2w[(lane << 3) | (i ^ swz)] = pack_f16(v0, v1);
      }
      asm volatile("s_waitcnt lgkmcnt(0)" ::: "memory");   // RAW: writes visible
      float a0 = 0.f, a1 = 0.f, a2 = 0.f, a3 = 0.f;
      float a4 = 0.f, a5 = 0.f, a6 = 0.f, a7 = 0.f;
#pragma unroll
      for (int c2 = 0; c2 < 64; ++c2) {
        const int cs = (c2 >> 2) & 7;              // constant after unroll
        unsigned wp = w3s[(c2 << 6) | lane];
        uint4 ra = *(const uint4*)&h2w[c2 << 3];
        uint4 rb = *(const uint4*)&h2w[(c2 << 3) + 4];
        unsigned hv[8] = {ra.x, ra.y, ra.z, ra.w, rb.x, rb.y, rb.z, rb.w};
        a0 = dot2(wp, hv[0 ^ cs], a0);
        a1 = dot2(wp, hv[1 ^ cs], a1);
        a2 = dot2(wp, hv[2 ^ cs], a2);
        a3 = dot2(wp, hv[3 ^ cs], a3);
        a4 = dot2(wp, hv[4 ^ cs], a4);
        a5 = dot2(wp, hv[5 ^ cs], a5);
        a6 = dot2(wp, hv[6 ^ cs], a6);
        a7 = dot2(wp, hv[7 ^ cs], a7);
      }
      s += (double)a0 + (double)a1 + (double)a2 + (double)a3
         + (double)a4 + (double)a5 + (double)a6 + (double)a7;
      s2 += (double)a0 * a0 + (double)a1 * a1 + (double)a2 * a2 + (double)a3 * a3
          + (double)a4 * a4 + (double)a5 * a5 + (double)a6 * a6 + (double)a7 * a7;
      mx = fmaxf(mx, fmaxf(fmaxf(a0, a1), fmaxf(a2, a3)));
      mx = fmaxf(mx, fmaxf(fmaxf(a4, a5), fmaxf(a6, a7)));
      mn = fminf(mn, fminf(fminf(a0, a1), fminf(a2, a3)));
      mn = fminf(mn, fminf(fminf(a4, a5), fminf(a6, a7)));
    }
    y3m[p * OC_ + lane] = pack_f16(mx, mn);
  }
  atomicAdd(&st3[lane], s);
  atomicAdd(&st3[64 + lane], s2);
}

// ---------------- conv3 finalize: out = lrelu(sc3*(sc3>=0?mx:mn)+off3) ---------
__global__ __launch_bounds__(256)
void fin3_kernel(const unsigned* __restrict__ y3m, const float* __restrict__ so3,
                 float* __restrict__ outp)
{
  int idx = blockIdx.x * 256 + threadIdx.x;
  if (idx >= B_ * N_ * OC_) return;
  int oo = idx & 63;
  float sc3 = so3[oo], off3 = so3[64 + oo];
  half2v hv = __builtin_bit_cast(half2v, y3m[idx]);
  float pick = (sc3 >= 0.f) ? (float)hv[0] : (float)hv[1];
  float v = fmaf(pick, sc3, off3);
  outp[idx] = v > 0.f ? v : 0.2f * v;
}

} // namespace

extern "C" void kernel_launch(void* const* d_in, const int* in_sizes, int n_in,
                              void* d_out, int out_size, void* d_ws, size_t ws_size,
                              hipStream_t stream) {
  const float* x   = (const float*)d_in[0];
  const float* pos = (const float*)d_in[1];
  const float* W1  = (const float*)d_in[2];
  const float* g1  = (const float*)d_in[3];
  const float* b1  = (const float*)d_in[4];
  const float* W2  = (const float*)d_in[5];
  const float* g2  = (const float*)d_in[6];
  const float* b2  = (const float*)d_in[7];
  const float* W3  = (const float*)d_in[8];
  const float* g3  = (const float*)d_in[9];
  const float* b3  = (const float*)d_in[10];

  float* outp = (float*)d_out;                 // [B*N*64] float
  float* oidx = outp + B_ * N_ * OC_;          // [B*N*32] idx2 as float values

  char* w = (char*)d_ws;
  double* stats = (double*)w;            w += 640 * sizeof(double);
  float* nxf    = (float*)w;             w += B_ * N_ * 4;
  float* WT1a   = (float*)w;             w += 64 * 128 * 4;
  float* WT1bm  = (float*)w;             w += 64 * 128 * 4;
  float* WT2a   = (float*)w;             w += 128 * 128 * 4;
  float* WT2bm  = (float*)w;             w += 128 * 128 * 4;
  unsigned* w3p = (unsigned*)w;          w += 64 * 64 * 4;
  float* so1    = (float*)w;             w += 256 * 4;
  float* so2    = (float*)w;             w += 256 * 4;
  float* so3    = (float*)w;             w += 128 * 4;
  int* idx1     = (int*)w;               w += B_ * N_ * K14_ * 4;
  int* idx2i    = (int*)w;               w += B_ * N_ * K2_ * 4;
  bf16* u       = (bf16*)w;              w += B_ * N_ * 128 * 2;
  bf16* uc      = (bf16*)w;              w += B_ * N_ * 128 * 2;
  bf16* h1      = (bf16*)w;              w += B_ * N_ * 128 * 2;
  bf16* zz  = u;    // alias: u dead after h1_kernel
  bf16* zzc = uc;   // alias: uc dead after h1_kernel
  unsigned* y3m = (unsigned*)h1;   // alias: h1 dead after lin<128> kernels (2 MB exact)

  hipMemsetAsync(stats, 0, 640 * sizeof(double), stream);

  xnorm_kernel<<<(B_ * N_ + 255) / 256, 256, 0, stream>>>(x, nxf);
  wprep_kernel<<<64, 256, 0, stream>>>(W1, W2, W3, WT1a, WT1bm, WT2a, WT2bm, w3p);

  knn_x_kernel<<<1024, 512, 0, stream>>>(x, nxf, idx1);
  knn_pos_kernel<<<1024, 512, 0, stream>>>(pos, idx1, idx2i, oidx);

  lin_kernel<64, float><<<2048, 256, 0, stream>>>(x, WT1a, u);
  lin_kernel<64, float><<<2048, 256, 0, stream>>>(x, WT1bm, uc);

  stats_gather_kernel<K14_><<<2048, 256, 0, stream>>>(u, uc, idx1, stats);
  bnfin_kernel<<<1, 128, 0, stream>>>(stats, g1, b1, so1, 128, (double)(B_ * N_ * K14_));
  h1_kernel<<<2048, 256, 0, stream>>>(u, uc, idx1, so1, h1);

  lin_kernel<128, bf16><<<2048, 256, 0, stream>>>(h1, WT2a, zz);
  lin_kernel<128, bf16><<<2048, 256, 0, stream>>>(h1, WT2bm, zzc);

  stats_gather_kernel<K2_><<<2048, 256, 0, stream>>>(zz, zzc, idx2i, stats + 256);
  bnfin_kernel<<<1, 128, 0, stream>>>(stats + 256, g2, b2, so2, 128, (double)(B_ * N_ * K2_));

  conv3s_kernel<<<1024, 256, 0, stream>>>(zz, zzc, idx2i, so2, w3p, stats + 512, y3m);
  bnfin_kernel<<<1, 128, 0, stream>>>(stats + 512, g3, b3, so3, 64, (double)(B_ * N_ * K2_));
  fin3_kernel<<<B_ * N_ * OC_ / 256, 256, 0, stream>>>(y3m, so3, outp);
}